// Round 2
// baseline (443.836 us; speedup 1.0000x reference)
//
#include <hip/hip_runtime.h>

// MS-SSIM, B=16 C=3 H=W=512, f32, win=11 sigma=1.5, 5 levels.
// Strategy: per level, fused separable-blur + ssim/cs + per-(b,c) reduction.
// acc layout in ws: [level][48][2] floats (ssim_sum, cs_sum), then pyramid buffers.

#define TW 32
#define TH 32
#define HALO 10
#define LW (TW + HALO)      // 42
#define LH (TH + HALO)      // 42
#define LSTR (LW + 1)       // 43, pad to decouple banks

// Gaussian window, size 11, sigma 1.5, normalized (computed in double, rounded).
__device__ __constant__ float G11[11] = {
    0.001028380f, 0.007598758f, 0.036000773f, 0.109360680f, 0.213005529f,
    0.266011731f,
    0.213005529f, 0.109360680f, 0.036000773f, 0.007598758f, 0.001028380f
};

__launch_bounds__(256)
__global__ void ssim_level_kernel(const float* __restrict__ X, const float* __restrict__ Y,
                                  int H, int W, int Hs, int Ws, float* __restrict__ acc)
{
    __shared__ float sx[LH * LSTR];
    __shared__ float sy[LH * LSTR];
    __shared__ float hq[5][LH * TW];
    __shared__ float red[2][4];

    const int bc  = blockIdx.z;
    const int ox  = blockIdx.x * TW;
    const int oy  = blockIdx.y * TH;
    const int tid = threadIdx.x;
    const size_t base = (size_t)bc * H * W;

    // ---- load 42x42 halo tile of X and Y (clamped; clamped texels are never
    // used by valid outputs, only by masked ones) ----
    for (int idx = tid; idx < LH * LW; idx += 256) {
        int r = idx / LW;
        int c = idx - r * LW;
        int gr = oy + r; if (gr > H - 1) gr = H - 1;
        int gc = ox + c; if (gc > W - 1) gc = W - 1;
        size_t g = base + (size_t)gr * W + gc;
        sx[r * LSTR + c] = X[g];
        sy[r * LSTR + c] = Y[g];
    }
    __syncthreads();

    // ---- horizontal 11-tap blur of {x, y, x*x, y*y, x*y} -> 5 LDS planes [42][32] ----
    for (int idx = tid; idx < LH * TW; idx += 256) {
        int r = idx >> 5;          // /32
        int c = idx & 31;
        const float* px = &sx[r * LSTR + c];
        const float* py = &sy[r * LSTR + c];
        float bx = 0.f, by = 0.f, bxx = 0.f, byy = 0.f, bxy = 0.f;
#pragma unroll
        for (int t = 0; t < 11; ++t) {
            float w  = G11[t];
            float xv = px[t];
            float yv = py[t];
            bx  += w * xv;
            by  += w * yv;
            bxx += w * xv * xv;
            byy += w * yv * yv;
            bxy += w * xv * yv;
        }
        hq[0][idx] = bx;  hq[1][idx] = by;
        hq[2][idx] = bxx; hq[3][idx] = byy; hq[4][idx] = bxy;
    }
    __syncthreads();

    // ---- vertical 11-tap blur + ssim/cs + accumulate ----
    float ssum = 0.f, csum = 0.f;
    const int tx = tid & 31;
    const int ty = tid >> 5;      // 0..7
    for (int rr = ty; rr < TH; rr += 8) {
        float m1 = 0.f, m2 = 0.f, qxx = 0.f, qyy = 0.f, qxy = 0.f;
#pragma unroll
        for (int t = 0; t < 11; ++t) {
            int o = (rr + t) * TW + tx;
            float w = G11[t];
            m1  += w * hq[0][o];
            m2  += w * hq[1][o];
            qxx += w * hq[2][o];
            qyy += w * hq[3][o];
            qxy += w * hq[4][o];
        }
        if (oy + rr < Hs && ox + tx < Ws) {
            const float C1 = 0.0001f, C2 = 0.0009f;
            float mu1s = m1 * m1, mu2s = m2 * m2, mu12 = m1 * m2;
            float s1  = qxx - mu1s;
            float s2  = qyy - mu2s;
            float s12 = qxy - mu12;
            float cs  = (2.f * s12 + C2) / (s1 + s2 + C2);
            float ss  = ((2.f * mu12 + C1) / (mu1s + mu2s + C1)) * cs;
            ssum += ss;
            csum += cs;
        }
    }

    // ---- block reduction: wave64 shfl, then cross-wave via LDS ----
#pragma unroll
    for (int off = 32; off; off >>= 1) {
        ssum += __shfl_down(ssum, off);
        csum += __shfl_down(csum, off);
    }
    if ((tid & 63) == 0) {
        red[0][tid >> 6] = ssum;
        red[1][tid >> 6] = csum;
    }
    __syncthreads();
    if (tid == 0) {
        float s = red[0][0] + red[0][1] + red[0][2] + red[0][3];
        float c = red[1][0] + red[1][1] + red[1][2] + red[1][3];
        atomicAdd(&acc[bc * 2 + 0], s);
        atomicAdd(&acc[bc * 2 + 1], c);
    }
}

// 2x2 avg-pool, stride 2, no padding (all level sizes even). Both tensors in one pass.
__launch_bounds__(256)
__global__ void down_kernel(const float* __restrict__ Xi, const float* __restrict__ Yi,
                            float* __restrict__ Xo, float* __restrict__ Yo,
                            int Ho, int Wo, int n)
{
    int idx = blockIdx.x * 256 + threadIdx.x;
    if (idx >= n) return;
    int w  = idx % Wo;
    int t  = idx / Wo;
    int h  = t % Ho;
    int bc = t / Ho;
    int W  = Wo * 2;
    size_t ib = (size_t)bc * (4 * Ho * Wo) + (size_t)(2 * h) * W + 2 * w;
    float2 a0 = *reinterpret_cast<const float2*>(Xi + ib);
    float2 a1 = *reinterpret_cast<const float2*>(Xi + ib + W);
    Xo[idx] = 0.25f * (a0.x + a0.y + a1.x + a1.y);
    float2 b0 = *reinterpret_cast<const float2*>(Yi + ib);
    float2 b1 = *reinterpret_cast<const float2*>(Yi + ib + W);
    Yo[idx] = 0.25f * (b0.x + b0.y + b1.x + b1.y);
}

// Final: per (b,c) compute prod over levels of relu(mean)^w, mean over 48, 1 - result.
__launch_bounds__(64)
__global__ void finalize_kernel(const float* __restrict__ acc, float* __restrict__ out)
{
    const int lane = threadIdx.x;
    float prod = 0.f;
    if (lane < 48) {
        const float npix[5] = {252004.f, 60516.f, 13924.f, 2916.f, 484.f};
        const float wgt[5]  = {0.0448f, 0.2856f, 0.3001f, 0.2363f, 0.1333f};
        prod = 1.f;
#pragma unroll
        for (int l = 0; l < 5; ++l) {
            // levels 0..3 use cs mean, level 4 uses ssim mean
            float v = (l < 4) ? acc[l * 96 + lane * 2 + 1] : acc[l * 96 + lane * 2 + 0];
            v = v / npix[l];
            v = fmaxf(v, 0.f);
            prod *= powf(v, wgt[l]);
        }
    }
#pragma unroll
    for (int off = 32; off; off >>= 1) prod += __shfl_down(prod, off);
    if (lane == 0) out[0] = 1.f - prod / 48.f;
}

extern "C" void kernel_launch(void* const* d_in, const int* in_sizes, int n_in,
                              void* d_out, int out_size, void* d_ws, size_t ws_size,
                              hipStream_t stream)
{
    const float* gen = (const float*)d_in[0];
    const float* gt  = (const float*)d_in[1];
    float* out = (float*)d_out;

    char* ws = (char*)d_ws;
    float* acc = (float*)ws;                 // 5*48*2 floats = 1920 B
    float* p   = (float*)(ws + 2048);
    float* g1 = p; p += (size_t)48 * 256 * 256;
    float* t1 = p; p += (size_t)48 * 256 * 256;
    float* g2 = p; p += (size_t)48 * 128 * 128;
    float* t2 = p; p += (size_t)48 * 128 * 128;
    float* g3 = p; p += (size_t)48 * 64 * 64;
    float* t3 = p; p += (size_t)48 * 64 * 64;
    float* g4 = p; p += (size_t)48 * 32 * 32;
    float* t4 = p; p += (size_t)48 * 32 * 32;

    hipMemsetAsync(acc, 0, 5 * 48 * 2 * sizeof(float), stream);

    auto launch_ssim = [&](const float* X, const float* Y, int H, int lvl) {
        int Hs = H - 10;
        dim3 grid((Hs + TW - 1) / TW, (Hs + TH - 1) / TH, 48);
        ssim_level_kernel<<<grid, 256, 0, stream>>>(X, Y, H, H, Hs, Hs, acc + lvl * 96);
    };
    auto launch_down = [&](const float* Xi, const float* Yi, float* Xo, float* Yo, int Ho) {
        int n = 48 * Ho * Ho;
        down_kernel<<<(n + 255) / 256, 256, 0, stream>>>(Xi, Yi, Xo, Yo, Ho, Ho, n);
    };

    launch_ssim(gen, gt, 512, 0);
    launch_down(gen, gt, g1, t1, 256);
    launch_ssim(g1, t1, 256, 1);
    launch_down(g1, t1, g2, t2, 128);
    launch_ssim(g2, t2, 128, 2);
    launch_down(g2, t2, g3, t3, 64);
    launch_ssim(g3, t3, 64, 3);
    launch_down(g3, t3, g4, t4, 32);
    launch_ssim(g4, t4, 32, 4);
    finalize_kernel<<<1, 64, 0, stream>>>(acc, out);
}